// Round 7
// baseline (68.875 us; speedup 1.0000x reference)
//
#include <hip/hip_runtime.h>
#include <stdint.h>

typedef __attribute__((ext_vector_type(8)))  __bf16        bf16x8;
typedef __attribute__((ext_vector_type(8)))  unsigned short u16x8;
typedef __attribute__((ext_vector_type(4)))  float          f32x4;
typedef __attribute__((ext_vector_type(16))) float          f32x16;
typedef __attribute__((ext_vector_type(4)))  unsigned int   u32x4;

#define NB 8
#define NC 64
#define NN 4096
#define NCHUNK 64
#define CHUNK_U16 4096   // 8KB per chunk per array
#define SPLITQ 4

#define EXP2F(x) __builtin_amdgcn_exp2f(x)

__device__ __forceinline__ unsigned short f2bf(float x) {
    unsigned int u = __builtin_bit_cast(unsigned int, x);
    u += 0x7fffu + ((u >> 16) & 1u);   // RNE
    return (unsigned short)(u >> 16);
}
// native-cast packed bf16 pair (compiler emits v_cvt_pk_bf16_f32)
__device__ __forceinline__ unsigned int pk2(float a, float b) {
    unsigned short x = __builtin_bit_cast(unsigned short, (__bf16)a);
    unsigned short y = __builtin_bit_cast(unsigned short, (__bf16)b);
    return (unsigned int)x | ((unsigned int)y << 16);
}

// ---------------- prepass: q,v fp32 -> bf16 fragments in ws ----------------
__global__ __launch_bounds__(256) void prepass(
    const float* __restrict__ qp, const float* __restrict__ vp,
    unsigned short* __restrict__ qfo, unsigned short* __restrict__ vfo)
{
    __shared__ float lt[64][68];
    const int orig = blockIdx.x;                   // XCD-swizzle: writes land on XCD=b
    const int bid = (orig & 7) * 64 + (orig >> 3); // b*64 + mc
    const int b = bid >> 6, mc = bid & 63;
    const int m0 = mc * 64;
    const int tid = threadIdx.x;
    const float* qb = qp + (size_t)b * NC * NN;
    const float* vb = vp + (size_t)b * NC * NN;
    unsigned short* qfc = qfo + (size_t)bid * CHUNK_U16;
    unsigned short* vfc = vfo + (size_t)bid * CHUNK_U16;

    #pragma unroll
    for (int rep = 0; rep < 4; ++rep) {
        int idx = tid + 256 * rep;
        int c = idx >> 4, m4 = (idx & 15) << 2;
        f32x4 xv = *reinterpret_cast<const f32x4*>(qb + (size_t)c * NN + m0 + m4);
        lt[m4+0][c] = xv[0]; lt[m4+1][c] = xv[1];
        lt[m4+2][c] = xv[2]; lt[m4+3][c] = xv[3];
    }
    __syncthreads();
    // q frag fid=(mt*4+kk)*64+l : elem e = q[c=16kk+8*(l>>5)+e][m0+32mt+(l&31)]
    #pragma unroll
    for (int rep = 0; rep < 2; ++rep) {
        int fid = tid + 256 * rep;
        int l = fid & 63, kk = (fid >> 6) & 3, mt = fid >> 8;
        int m = 32 * mt + (l & 31), c0 = 16 * kk + 8 * (l >> 5);
        u16x8 ov;
        #pragma unroll
        for (int e = 0; e < 8; ++e) ov[e] = f2bf(lt[m][c0 + e]);
        *reinterpret_cast<u16x8*>(qfc + (size_t)fid * 8) = ov;
    }
    __syncthreads();
    #pragma unroll
    for (int rep = 0; rep < 4; ++rep) {
        int idx = tid + 256 * rep;
        int c = idx >> 4, m4 = (idx & 15) << 2;
        f32x4 xv = *reinterpret_cast<const f32x4*>(vb + (size_t)c * NN + m0 + m4);
        *reinterpret_cast<f32x4*>(&lt[c][m4]) = xv;
    }
    __syncthreads();
    // v frag fid=(ct*4+kt)*64+l : elem e = v[c=32ct+(l&31)][m0+16kt+8*(l>>5)+e]
    #pragma unroll
    for (int rep = 0; rep < 2; ++rep) {
        int fid = tid + 256 * rep;
        int l = fid & 63, kt = (fid >> 6) & 3, ct = fid >> 8;
        int c = 32 * ct + (l & 31), mm = 16 * kt + 8 * (l >> 5);
        u16x8 ov;
        #pragma unroll
        for (int e = 0; e < 8; ++e) ov[e] = f2bf(lt[c][mm + e]);
        *reinterpret_cast<u16x8*>(vfc + (size_t)fid * 8) = ov;
    }
}

// ---- 4-wave LDS-shared split-m flash: 32 rows/wave, ds_read imm offsets ----
template<int SPLITQ_T>
__global__ __launch_bounds__(256, 3) void attn7(
    const float* __restrict__ kp,
    const unsigned short* __restrict__ qfo,
    const unsigned short* __restrict__ vfo,
    float* __restrict__ part, float* __restrict__ lp)
{
    constexpr int CPQ_T = NCHUNK / SPLITQ_T;      // 16
    constexpr int TG = NN / 128;                   // 32 tile-groups (128 rows/block)
    constexpr int PER_XCD = SPLITQ_T * TG;         // 128 (NB==8 -> batch==XCD)
    __shared__ unsigned short sb[2][2 * CHUNK_U16]; // 32KB: [buf][ q(4096) | v(4096) ]

    const int orig = blockIdx.x;                   // 1024 wg
    const int bid  = (orig & 7) * PER_XCD + (orig >> 3);
    const int b    = bid / PER_XCD;
    const int rest = bid % PER_XCD;
    const int qid  = rest / TG;                    // qid-major: neighbors share chunks
    const int tg   = rest % TG;
    const int bn0  = tg * 128;
    const int tid = threadIdx.x;
    const int w = tid >> 6, l = tid & 63;
    const int lo5 = l & 31, hi = l >> 5;
    const int nrow = bn0 + 32 * w + lo5;           // this wave's softmax row n

    // K B-frags for this wave's 32 rows; scale*log2e folded in
    const float kscale = 0.125f * 1.44269504088896f;
    const float* kb = kp + (size_t)b * NC * NN;
    bf16x8 kf[4];
    #pragma unroll
    for (int kk = 0; kk < 4; ++kk) {
        u16x8 t;
        #pragma unroll
        for (int e = 0; e < 8; ++e)
            t[e] = __builtin_bit_cast(unsigned short,
                      (__bf16)(kscale * kb[(size_t)(16 * kk + 8 * hi + e) * NN + nrow]));
        kf[kk] = __builtin_bit_cast(bf16x8, t);
    }

    const unsigned short* qg = qfo + (size_t)(b * NCHUNK + qid * CPQ_T) * CHUNK_U16;
    const unsigned short* vg = vfo + (size_t)(b * NCHUNK + qid * CPQ_T) * CHUNK_U16;

    // each wave stages its quarter (2KB q + 2KB v) -> 4 global_load_lds / wave / iter
    auto stage = [&](int mcr, int buf) {
        const unsigned short* gq = qg + (size_t)mcr * CHUNK_U16;
        const unsigned short* gv = vg + (size_t)mcr * CHUNK_U16;
        #pragma unroll
        for (int j = 0; j < 2; ++j) {
            int off = w * 1024 + j * 512 + l * 8;   // u16 units
            __builtin_amdgcn_global_load_lds(
                (const __attribute__((address_space(1))) void*)(gq + off),
                (__attribute__((address_space(3))) void*)(&sb[buf][w * 1024 + j * 512]),
                16, 0, 0);
            __builtin_amdgcn_global_load_lds(
                (const __attribute__((address_space(1))) void*)(gv + off),
                (__attribute__((address_space(3))) void*)(&sb[buf][CHUNK_U16 + w * 1024 + j * 512]),
                16, 0, 0);
        }
    };

    stage(0, 0);
    __syncthreads();

    f32x16 zro;
    #pragma unroll
    for (int r = 0; r < 16; ++r) zro[r] = 0.f;
    f32x16 o0 = zro, o1 = zro;
    float sum = 0.f;

    for (int mcr = 0; mcr < CPQ_T; ++mcr) {
        const int cur = mcr & 1;
        if (mcr + 1 < CPQ_T) stage(mcr + 1, cur ^ 1);   // WAR-safe: barrier closed i-1
        const unsigned short* qb_ = &sb[cur][0];
        const unsigned short* vb_ = &sb[cur][CHUNK_U16];

        // q frags: ds_read_b128 at immediate offsets
        u16x8 a[8];
        #pragma unroll
        for (int f = 0; f < 8; ++f)
            a[f] = *reinterpret_cast<const u16x8*>(qb_ + (f * 64 + l) * 8);

        // ---- QK^T: S^T[m 0..63][n = this wave's 32], first kk uses zero C
        f32x16 s0 = __builtin_amdgcn_mfma_f32_32x32x16_bf16(__builtin_bit_cast(bf16x8, a[0]), kf[0], zro, 0, 0, 0);
        f32x16 s1 = __builtin_amdgcn_mfma_f32_32x32x16_bf16(__builtin_bit_cast(bf16x8, a[4]), kf[0], zro, 0, 0, 0);
        #pragma unroll
        for (int kk = 1; kk < 4; ++kk) {
            s0 = __builtin_amdgcn_mfma_f32_32x32x16_bf16(__builtin_bit_cast(bf16x8, a[kk]),     kf[kk], s0, 0, 0, 0);
            s1 = __builtin_amdgcn_mfma_f32_32x32x16_bf16(__builtin_bit_cast(bf16x8, a[4 + kk]), kf[kk], s1, 0, 0, 0);
        }

        // v frags reuse a[] (q consumed) — issued before exp2 phase to hide ds latency
        #pragma unroll
        for (int f = 0; f < 8; ++f)
            a[f] = *reinterpret_cast<const u16x8*>(vb_ + (f * 64 + l) * 8);

        // ---- no-max softmax: p = exp2(s) (offset cancels in O/l); deferred x-half sum
        #pragma unroll
        for (int r = 0; r < 16; ++r) { s0[r] = EXP2F(s0[r]); sum += s0[r]; }
        #pragma unroll
        for (int r = 0; r < 16; ++r) { s1[r] = EXP2F(s1[r]); sum += s1[r]; }

        // ---- PV: pack bf16, exchange only partner-needed words (2 shfl/kt)
        #pragma unroll
        for (int kt = 0; kt < 4; ++kt) {
            const f32x16& sm = (kt < 2) ? s0 : s1;
            const int qA = 2 * (kt & 1);
            unsigned int wA0 = pk2(sm[4*qA+0], sm[4*qA+1]);
            unsigned int wA1 = pk2(sm[4*qA+2], sm[4*qA+3]);
            unsigned int wB0 = pk2(sm[4*qA+4], sm[4*qA+5]);
            unsigned int wB1 = pk2(sm[4*qA+6], sm[4*qA+7]);
            unsigned int e0 = (unsigned int)__shfl_xor((int)(hi ? wA0 : wB0), 32);
            unsigned int e1 = (unsigned int)__shfl_xor((int)(hi ? wA1 : wB1), 32);
            u32x4 pf = hi ? (u32x4){e0, e1, wB0, wB1} : (u32x4){wA0, wA1, e0, e1};
            bf16x8 pB = __builtin_bit_cast(bf16x8, pf);
            o0 = __builtin_amdgcn_mfma_f32_32x32x16_bf16(__builtin_bit_cast(bf16x8, a[kt]),     pB, o0, 0, 0, 0);
            o1 = __builtin_amdgcn_mfma_f32_32x32x16_bf16(__builtin_bit_cast(bf16x8, a[4 + kt]), pB, o1, 0, 0, 0);
        }
        __syncthreads();   // drains vmcnt (next buf staged) + closes reads of cur
    }

    // ---- epilogue: partial O^T [64ch][64row] slices + l
    sum += (float)__shfl_xor(sum, 32);
    const int t64 = (bn0 >> 6) + (w >> 1);     // 64-row tile index
    const int rowoff = 32 * (w & 1);
    const int pidx = (b * 64 + t64) * SPLITQ_T + qid;
    float* po = part + (size_t)pidx * 4096;
    #pragma unroll
    for (int r = 0; r < 16; ++r) {
        int cb = (r & 3) + 8 * (r >> 2) + 4 * hi;
        po[cb * 64 + rowoff + lo5]        = o0[r];
        po[(32 + cb) * 64 + rowoff + lo5] = o1[r];
    }
    if (hi == 0) lp[(size_t)pidx * 64 + rowoff + lo5] = sum;
}

// ------------- combine: plain sum of partials -------------
__global__ __launch_bounds__(256) void combine2(
    const float* __restrict__ part, const float* __restrict__ lp,
    float* __restrict__ outp, int splitq)
{
    __shared__ float sinv[64];
    const int orig = blockIdx.x;                   // XCD-swizzle: read XCD-local partials
    const int bid = (orig & 7) * 64 + (orig >> 3); // 512: b*64 + tile
    const int b = bid >> 6, tile = bid & 63;
    const int n0 = tile * 64;
    const int t = threadIdx.x;
    const int pb = bid * splitq;

    if (t < 64) {
        float L = 0.f;
        for (int q = 0; q < splitq; ++q) L += lp[(size_t)(pb + q) * 64 + t];
        sinv[t] = 1.0f / L;
    }
    __syncthreads();

    float* ob = outp + (size_t)b * NC * NN;
    #pragma unroll
    for (int it = 0; it < 4; ++it) {
        int idx = it * 1024 + t * 4;
        int ch = idx >> 6, r0 = idx & 63;
        f32x4 acc = (f32x4){0.f, 0.f, 0.f, 0.f};
        for (int q = 0; q < splitq; ++q) {
            f32x4 v = *reinterpret_cast<const f32x4*>(part + (size_t)(pb + q) * 4096 + idx);
            acc += v;
        }
        f32x4 res;
        #pragma unroll
        for (int u = 0; u < 4; ++u) res[u] = acc[u] * sinv[r0 + u];
        *reinterpret_cast<f32x4*>(ob + (size_t)ch * NN + n0 + r0) = res;
    }
}

// ---------------- non-split attn2 (verified R3 fallback) ----------------
__global__ __launch_bounds__(128) void attn2(
    const float* __restrict__ kp,
    const unsigned short* __restrict__ qfo,
    const unsigned short* __restrict__ vfo,
    float* __restrict__ outp)
{
    __shared__ unsigned short sb[2][2 * CHUNK_U16];
    const int orig = blockIdx.x;
    const int bid  = (orig & 7) * 64 + (orig >> 3);
    const int b = bid >> 6, nt = bid & 63;
    const int n0 = nt * 64;
    const int tid = threadIdx.x;
    const int w = tid >> 6, l = tid & 63;
    const int lo5 = l & 31, hi = l >> 5;
    const int nrow = n0 + 32 * w + lo5;
    const float kscale = 0.125f * 1.44269504088896f;
    const float* kb = kp + (size_t)b * NC * NN;
    bf16x8 kf[4];
    #pragma unroll
    for (int kk = 0; kk < 4; ++kk) {
        u16x8 t;
        #pragma unroll
        for (int e = 0; e < 8; ++e)
            t[e] = f2bf(kscale * kb[(size_t)(16 * kk + 8 * hi + e) * NN + nrow]);
        kf[kk] = __builtin_bit_cast(bf16x8, t);
    }
    const unsigned short* qg = qfo + (size_t)(b * 64) * CHUNK_U16;
    const unsigned short* vg = vfo + (size_t)(b * 64) * CHUNK_U16;
    auto stage = [&](int mc, int buf) {
        const unsigned short* gq = qg + (size_t)mc * CHUNK_U16;
        const unsigned short* gv = vg + (size_t)mc * CHUNK_U16;
        #pragma unroll
        for (int i = 0; i < 4; ++i) {
            int seg = w * 4 + i;
            int off = seg * 512 + l * 8;
            __builtin_amdgcn_global_load_lds(
                (const __attribute__((address_space(1))) void*)(gq + off),
                (__attribute__((address_space(3))) void*)(&sb[buf][seg * 512]), 16, 0, 0);
            __builtin_amdgcn_global_load_lds(
                (const __attribute__((address_space(1))) void*)(gv + off),
                (__attribute__((address_space(3))) void*)(&sb[buf][CHUNK_U16 + seg * 512]), 16, 0, 0);
        }
    };
    stage(0, 0);
    __syncthreads();
    f32x16 o0, o1;
    #pragma unroll
    for (int r = 0; r < 16; ++r) { o0[r] = 0.f; o1[r] = 0.f; }
    float m_run = -1e30f, l_run = 0.f;
    for (int mc = 0; mc < NCHUNK; ++mc) {
        const int cur = mc & 1;
        if (mc + 1 < NCHUNK) stage(mc + 1, cur ^ 1);
        const unsigned short* qb_ = &sb[cur][0];
        const unsigned short* vb_ = &sb[cur][CHUNK_U16];
        f32x16 s0, s1;
        #pragma unroll
        for (int r = 0; r < 16; ++r) { s0[r] = 0.f; s1[r] = 0.f; }
        #pragma unroll
        for (int kk = 0; kk < 4; ++kk) {
            u16x8 a0 = *reinterpret_cast<const u16x8*>(qb_ + ((0 * 4 + kk) * 64 + l) * 8);
            u16x8 a1 = *reinterpret_cast<const u16x8*>(qb_ + ((1 * 4 + kk) * 64 + l) * 8);
            s0 = __builtin_amdgcn_mfma_f32_32x32x16_bf16(__builtin_bit_cast(bf16x8, a0), kf[kk], s0, 0, 0, 0);
            s1 = __builtin_amdgcn_mfma_f32_32x32x16_bf16(__builtin_bit_cast(bf16x8, a1), kf[kk], s1, 0, 0, 0);
        }
        float pmax = s0[0];
        #pragma unroll
        for (int r = 1; r < 16; ++r) pmax = fmaxf(pmax, s0[r]);
        #pragma unroll
        for (int r = 0; r < 16; ++r) pmax = fmaxf(pmax, s1[r]);
        pmax = fmaxf(pmax, (float)__shfl_xor(pmax, 32));
        const float mn = fmaxf(m_run, pmax);
        const float alpha = EXP2F(m_run - mn);
        float sum = 0.f;
        #pragma unroll
        for (int r = 0; r < 16; ++r) { s0[r] = EXP2F(s0[r] - mn); sum += s0[r]; }
        #pragma unroll
        for (int r = 0; r < 16; ++r) { s1[r] = EXP2F(s1[r] - mn); sum += s1[r]; }
        sum += (float)__shfl_xor(sum, 32);
        l_run = l_run * alpha + sum;
        m_run = mn;
        #pragma unroll
        for (int r = 0; r < 16; ++r) { o0[r] *= alpha; o1[r] *= alpha; }
        #pragma unroll
        for (int kt = 0; kt < 4; ++kt) {
            const f32x16& sm = (kt < 2) ? s0 : s1;
            const int qA = 2 * (kt & 1);
            unsigned int dA0 = pk2(sm[4 * qA + 0], sm[4 * qA + 1]);
            unsigned int dA1 = pk2(sm[4 * qA + 2], sm[4 * qA + 3]);
            unsigned int dB0 = pk2(sm[4 * qA + 4], sm[4 * qA + 5]);
            unsigned int dB1 = pk2(sm[4 * qA + 6], sm[4 * qA + 7]);
            unsigned int sA0 = (unsigned int)__shfl_xor((int)dA0, 32);
            unsigned int sA1 = (unsigned int)__shfl_xor((int)dA1, 32);
            unsigned int sB0 = (unsigned int)__shfl_xor((int)dB0, 32);
            unsigned int sB1 = (unsigned int)__shfl_xor((int)dB1, 32);
            u32x4 pf;
            if (hi == 0) pf = (u32x4){dA0, dA1, sA0, sA1};
            else         pf = (u32x4){sB0, sB1, dB0, dB1};
            bf16x8 pB = __builtin_bit_cast(bf16x8, pf);
            u16x8 v0 = *reinterpret_cast<const u16x8*>(vb_ + ((0 * 4 + kt) * 64 + l) * 8);
            u16x8 v1 = *reinterpret_cast<const u16x8*>(vb_ + ((1 * 4 + kt) * 64 + l) * 8);
            o0 = __builtin_amdgcn_mfma_f32_32x32x16_bf16(__builtin_bit_cast(bf16x8, v0), pB, o0, 0, 0, 0);
            o1 = __builtin_amdgcn_mfma_f32_32x32x16_bf16(__builtin_bit_cast(bf16x8, v1), pB, o1, 0, 0, 0);
        }
        __syncthreads();
    }
    const float inv = 1.0f / l_run;
    float* ob = outp + (size_t)b * NC * NN;
    #pragma unroll
    for (int r = 0; r < 16; ++r) {
        int cb = (r & 3) + 8 * (r >> 2) + 4 * hi;
        ob[(size_t)cb * NN + n0 + 32 * w + lo5]        = o0[r] * inv;
        ob[(size_t)(32 + cb) * NN + n0 + 32 * w + lo5] = o1[r] * inv;
    }
}

// ---------------- round-1 fallback (no ws) ----------------
__global__ __launch_bounds__(256) void attn_fwd(
    const float* __restrict__ kp, const float* __restrict__ qp,
    const float* __restrict__ vp, float* __restrict__ outp)
{
    __shared__ unsigned short qs[8][64][8];
    __shared__ unsigned short vs[8][64][8];
    __shared__ unsigned short ps[4][2][64][8];
    const int orig = blockIdx.x;
    const int bid  = (orig & 7) * 64 + (orig >> 3);
    const int b  = bid >> 6;
    const int n0 = (bid & 63) * 64;
    const int tid = threadIdx.x;
    const int w = tid >> 6, l = tid & 63, g = l >> 4, j = l & 15;
    const float* kb = kp + (size_t)b * NC * NN;
    const float* qb = qp + (size_t)b * NC * NN;
    const float* vb = vp + (size_t)b * NC * NN;
    bf16x8 ak[2];
    #pragma unroll
    for (int kk = 0; kk < 2; ++kk) {
        u16x8 tmp;
        #pragma unroll
        for (int e = 0; e < 8; ++e)
            tmp[e] = f2bf(kb[(size_t)(32*kk + 8*g + e) * NN + (n0 + 16*w + j)]);
        ak[kk] = __builtin_bit_cast(bf16x8, tmp);
    }
    f32x4 o[4];
    float m_run[4], l_run[4];
    #pragma unroll
    for (int ct = 0; ct < 4; ++ct) o[ct] = (f32x4){0.f,0.f,0.f,0.f};
    #pragma unroll
    for (int r = 0; r < 4; ++r) { m_run[r] = -1e30f; l_run[r] = 0.0f; }
    for (int m0 = 0; m0 < NN; m0 += 64) {
        __syncthreads();
        #pragma unroll
        for (int it = 0; it < 4; ++it) {
            int f = tid + 256*it;
            int c = f >> 4, m4 = (f & 15) << 2;
            f32x4 qv = *reinterpret_cast<const f32x4*>(qb + (size_t)c*NN + m0 + m4);
            f32x4 vv = *reinterpret_cast<const f32x4*>(vb + (size_t)c*NN + m0 + m4);
            int kkq = c >> 5, eq = c & 7, gq = (c >> 3) & 3, tq = m4 >> 4;
            #pragma unroll
            for (int u = 0; u < 4; ++u)
                qs[kkq*4 + tq][16*gq + ((m4 + u) & 15)][eq] = f2bf(qv[u]);
            int ctv = c >> 4, jv = c & 15, kkv = m4 >> 5, gv = (m4 >> 3) & 3, ev = m4 & 7;
            #pragma unroll
            for (int u = 0; u < 4; ++u)
                vs[kkv*4 + ctv][16*gv + jv][ev + u] = f2bf(vv[u]);
        }
        __syncthreads();
        f32x4 s[4];
        #pragma unroll
        for (int t = 0; t < 4; ++t) {
            f32x4 acc = (f32x4){0.f,0.f,0.f,0.f};
            #pragma unroll
            for (int kk = 0; kk < 2; ++kk) {
                u16x8 raw = *reinterpret_cast<const u16x8*>(&qs[kk*4 + t][l][0]);
                acc = __builtin_amdgcn_mfma_f32_16x16x32_bf16(ak[kk], __builtin_bit_cast(bf16x8, raw), acc, 0,0,0);
            }
            s[t] = acc * 0.125f;
        }
        float alpha[4];
        #pragma unroll
        for (int r = 0; r < 4; ++r) {
            float m1 = fmaxf(fmaxf(s[0][r], s[1][r]), fmaxf(s[2][r], s[3][r]));
            #pragma unroll
            for (int off = 1; off < 16; off <<= 1) m1 = fmaxf(m1, __shfl_xor(m1, off));
            float mn = fmaxf(m_run[r], m1);
            alpha[r] = __expf(m_run[r] - mn);
            m_run[r] = mn;
            float acc = 0.0f;
            #pragma unroll
            for (int t = 0; t < 4; ++t) { float p = __expf(s[t][r] - mn); s[t][r] = p; acc += p; }
            #pragma unroll
            for (int off = 1; off < 16; off <<= 1) acc += __shfl_xor(acc, off);
            l_run[r] = l_run[r] * alpha[r] + acc;
        }
        {
            int srcl = (j >> 2) << 4;
            float a0 = __shfl(alpha[0], srcl), a1 = __shfl(alpha[1], srcl);
            float a2 = __shfl(alpha[2], srcl), a3 = __shfl(alpha[3], srcl);
            int rs = j & 3;
            float ac = (rs==0)?a0:(rs==1)?a1:(rs==2)?a2:a3;
            #pragma unroll
            for (int ct = 0; ct < 4; ++ct) o[ct] *= ac;
        }
        #pragma unroll
        for (int t = 0; t < 4; ++t) {
            int m = 16*t + j;
            #pragma unroll
            for (int r = 0; r < 4; ++r)
                ps[w][m >> 5][((m >> 3) & 3)*16 + 4*g + r][m & 7] = f2bf(s[t][r]);
        }
        asm volatile("s_waitcnt lgkmcnt(0)" ::: "memory");
        #pragma unroll
        for (int kk2 = 0; kk2 < 2; ++kk2) {
            u16x8 rp = *reinterpret_cast<const u16x8*>(&ps[w][kk2][l][0]);
            bf16x8 bp = __builtin_bit_cast(bf16x8, rp);
            #pragma unroll
            for (int ct = 0; ct < 4; ++ct) {
                u16x8 rv = *reinterpret_cast<const u16x8*>(&vs[kk2*4 + ct][l][0]);
                o[ct] = __builtin_amdgcn_mfma_f32_16x16x32_bf16(__builtin_bit_cast(bf16x8, rv), bp, o[ct], 0,0,0);
            }
        }
    }
    {
        int srcl = (j >> 2) << 4;
        float l0 = __shfl(l_run[0], srcl), l1 = __shfl(l_run[1], srcl);
        float l2 = __shfl(l_run[2], srcl), l3 = __shfl(l_run[3], srcl);
        int rs = j & 3;
        float lc = (rs==0)?l0:(rs==1)?l1:(rs==2)?l2:l3;
        float inv = 1.0f / lc;
        #pragma unroll
        for (int ct = 0; ct < 4; ++ct)
            #pragma unroll
            for (int r = 0; r < 4; ++r)
                outp[(size_t)b*NC*NN + (size_t)(16*ct + 4*g + r)*NN + (n0 + 16*w + j)] = o[ct][r] * inv;
    }
}

extern "C" void kernel_launch(void* const* d_in, const int* in_sizes, int n_in,
                              void* d_out, int out_size, void* d_ws, size_t ws_size,
                              hipStream_t stream) {
    const float* kp = (const float*)d_in[0];
    const float* qp = (const float*)d_in[1];
    const float* vp = (const float*)d_in[2];
    float* op = (float*)d_out;
    const size_t FRAG_BYTES = (size_t)2 * NB * NCHUNK * CHUNK_U16 * sizeof(unsigned short); // 8 MB
    unsigned short* qfo = (unsigned short*)d_ws;
    unsigned short* vfo = qfo + (size_t)NB * NCHUNK * CHUNK_U16;

    const size_t NEED = FRAG_BYTES
        + (size_t)NB * 64 * SPLITQ * 4096 * sizeof(float)   // partials (32 MB)
        + (size_t)NB * 64 * SPLITQ * 64 * sizeof(float);    // l sums

    if (ws_size >= NEED) {
        float* part = (float*)((char*)d_ws + FRAG_BYTES);
        float* lpp  = part + (size_t)NB * 64 * SPLITQ * 4096;
        hipLaunchKernelGGL(prepass, dim3(NB * NCHUNK), dim3(256), 0, stream, qp, vp, qfo, vfo);
        hipLaunchKernelGGL(attn7<SPLITQ>, dim3(NB * SPLITQ * (NN / 128)), dim3(256), 0, stream,
                           kp, qfo, vfo, part, lpp);
        hipLaunchKernelGGL(combine2, dim3(NB * 64), dim3(256), 0, stream, part, lpp, op, SPLITQ);
    } else if (ws_size >= FRAG_BYTES) {
        hipLaunchKernelGGL(prepass, dim3(NB * NCHUNK), dim3(256), 0, stream, qp, vp, qfo, vfo);
        hipLaunchKernelGGL(attn2, dim3(NB * NCHUNK), dim3(128), 0, stream, kp, qfo, vfo, op);
    } else {
        hipLaunchKernelGGL(attn_fwd, dim3(512), dim3(256), 0, stream, kp, qp, vp, op);
    }
}

// Round 8
// 65.730 us; speedup vs baseline: 1.0478x; 1.0478x over previous
//
#include <hip/hip_runtime.h>
#include <stdint.h>

typedef __attribute__((ext_vector_type(8)))  __bf16        bf16x8;
typedef __attribute__((ext_vector_type(8)))  unsigned short u16x8;
typedef __attribute__((ext_vector_type(4)))  float          f32x4;
typedef __attribute__((ext_vector_type(16))) float          f32x16;
typedef __attribute__((ext_vector_type(4)))  unsigned int   u32x4;

#define NB 8
#define NC 64
#define NN 4096
#define NCHUNK 64
#define CHUNK_U16 4096   // 8KB per chunk per array
#define SPLITQ 4

#define EXP2F(x) __builtin_amdgcn_exp2f(x)

__device__ __forceinline__ unsigned short f2bf(float x) {
    unsigned int u = __builtin_bit_cast(unsigned int, x);
    u += 0x7fffu + ((u >> 16) & 1u);   // RNE
    return (unsigned short)(u >> 16);
}
// native-cast packed bf16 pair (compiler emits v_cvt_pk_bf16_f32)
__device__ __forceinline__ unsigned int pk2(float a, float b) {
    unsigned short x = __builtin_bit_cast(unsigned short, (__bf16)a);
    unsigned short y = __builtin_bit_cast(unsigned short, (__bf16)b);
    return (unsigned int)x | ((unsigned int)y << 16);
}

// ---------------- prepass: q,v fp32 -> bf16 fragments in ws ----------------
__global__ __launch_bounds__(256) void prepass(
    const float* __restrict__ qp, const float* __restrict__ vp,
    unsigned short* __restrict__ qfo, unsigned short* __restrict__ vfo)
{
    __shared__ float lt[64][68];
    const int orig = blockIdx.x;                   // XCD-swizzle: writes land on XCD=b
    const int bid = (orig & 7) * 64 + (orig >> 3); // b*64 + mc
    const int b = bid >> 6, mc = bid & 63;
    const int m0 = mc * 64;
    const int tid = threadIdx.x;
    const float* qb = qp + (size_t)b * NC * NN;
    const float* vb = vp + (size_t)b * NC * NN;
    unsigned short* qfc = qfo + (size_t)bid * CHUNK_U16;
    unsigned short* vfc = vfo + (size_t)bid * CHUNK_U16;

    #pragma unroll
    for (int rep = 0; rep < 4; ++rep) {
        int idx = tid + 256 * rep;
        int c = idx >> 4, m4 = (idx & 15) << 2;
        f32x4 xv = *reinterpret_cast<const f32x4*>(qb + (size_t)c * NN + m0 + m4);
        lt[m4+0][c] = xv[0]; lt[m4+1][c] = xv[1];
        lt[m4+2][c] = xv[2]; lt[m4+3][c] = xv[3];
    }
    __syncthreads();
    // q frag fid=(mt*4+kk)*64+l : elem e = q[c=16kk+8*(l>>5)+e][m0+32mt+(l&31)]
    #pragma unroll
    for (int rep = 0; rep < 2; ++rep) {
        int fid = tid + 256 * rep;
        int l = fid & 63, kk = (fid >> 6) & 3, mt = fid >> 8;
        int m = 32 * mt + (l & 31), c0 = 16 * kk + 8 * (l >> 5);
        u16x8 ov;
        #pragma unroll
        for (int e = 0; e < 8; ++e) ov[e] = f2bf(lt[m][c0 + e]);
        *reinterpret_cast<u16x8*>(qfc + (size_t)fid * 8) = ov;
    }
    __syncthreads();
    #pragma unroll
    for (int rep = 0; rep < 4; ++rep) {
        int idx = tid + 256 * rep;
        int c = idx >> 4, m4 = (idx & 15) << 2;
        f32x4 xv = *reinterpret_cast<const f32x4*>(vb + (size_t)c * NN + m0 + m4);
        *reinterpret_cast<f32x4*>(&lt[c][m4]) = xv;
    }
    __syncthreads();
    // v frag fid=(ct*4+kt)*64+l : elem e = v[c=32ct+(l&31)][m0+16kt+8*(l>>5)+e]
    #pragma unroll
    for (int rep = 0; rep < 2; ++rep) {
        int fid = tid + 256 * rep;
        int l = fid & 63, kt = (fid >> 6) & 3, ct = fid >> 8;
        int c = 32 * ct + (l & 31), mm = 16 * kt + 8 * (l >> 5);
        u16x8 ov;
        #pragma unroll
        for (int e = 0; e < 8; ++e) ov[e] = f2bf(lt[c][mm + e]);
        *reinterpret_cast<u16x8*>(vfc + (size_t)fid * 8) = ov;
    }
}

// ---- R8: 4-wave blocks, q via LDS dbuf, v global->reg, permlane32_swap PV ----
template<int SPLITQ_T>
__global__ __launch_bounds__(256, 3) void attn8(
    const float* __restrict__ kp,
    const unsigned short* __restrict__ qfo,
    const unsigned short* __restrict__ vfo,
    float* __restrict__ part, float* __restrict__ lp)
{
    constexpr int CPQ_T = NCHUNK / SPLITQ_T;      // 16
    constexpr int TG = NN / 128;                   // 32 tile-groups (128 rows/block)
    constexpr int PER_XCD = SPLITQ_T * TG;         // 128 (NB==8 -> batch==XCD)
    __shared__ unsigned short sq[2][CHUNK_U16];    // 16KB: q only, double-buffered

    const int orig = blockIdx.x;                   // 1024 wg
    const int bid  = (orig & 7) * PER_XCD + (orig >> 3);
    const int b    = bid / PER_XCD;
    const int rest = bid % PER_XCD;
    const int qid  = rest / TG;                    // qid-major: neighbors share chunks
    const int tg   = rest % TG;
    const int bn0  = tg * 128;
    const int tid = threadIdx.x;
    const int w = tid >> 6, l = tid & 63;
    const int lo5 = l & 31, hi = l >> 5;
    const int nrow = bn0 + 32 * w + lo5;           // this wave's softmax row n

    // K B-frags for this wave's 32 rows; scale*log2e folded in
    const float kscale = 0.125f * 1.44269504088896f;
    const float* kb = kp + (size_t)b * NC * NN;
    bf16x8 kf[4];
    #pragma unroll
    for (int kk = 0; kk < 4; ++kk) {
        u16x8 t;
        #pragma unroll
        for (int e = 0; e < 8; ++e)
            t[e] = __builtin_bit_cast(unsigned short,
                      (__bf16)(kscale * kb[(size_t)(16 * kk + 8 * hi + e) * NN + nrow]));
        kf[kk] = __builtin_bit_cast(bf16x8, t);
    }

    const unsigned short* qg = qfo + (size_t)(b * NCHUNK + qid * CPQ_T) * CHUNK_U16;
    const unsigned short* vg = vfo + (size_t)(b * NCHUNK + qid * CPQ_T) * CHUNK_U16;

    // each wave stages its quarter of q (2KB) -> 2 global_load_lds / wave / iter
    auto stage_q = [&](int mcr, int buf) {
        const unsigned short* gq = qg + (size_t)mcr * CHUNK_U16;
        #pragma unroll
        for (int j = 0; j < 2; ++j) {
            int off = w * 1024 + j * 512 + l * 8;   // u16 units
            __builtin_amdgcn_global_load_lds(
                (const __attribute__((address_space(1))) void*)(gq + off),
                (__attribute__((address_space(3))) void*)(&sq[buf][w * 1024 + j * 512]),
                16, 0, 0);
        }
    };

    stage_q(0, 0);
    __syncthreads();

    f32x16 zro;
    #pragma unroll
    for (int r = 0; r < 16; ++r) zro[r] = 0.f;
    f32x16 o0 = zro, o1 = zro;
    float sum = 0.f;

    for (int mcr = 0; mcr < CPQ_T; ++mcr) {
        const int cur = mcr & 1;
        if (mcr + 1 < CPQ_T) stage_q(mcr + 1, cur ^ 1);  // WAR-safe: barrier closed i-1
        const unsigned short* qb_ = &sq[cur][0];
        const unsigned short* vc  = vg + (size_t)mcr * CHUNK_U16;

        // q frags: ds_read_b128 at immediate offsets
        u16x8 a[8];
        #pragma unroll
        for (int f = 0; f < 8; ++f)
            a[f] = *reinterpret_cast<const u16x8*>(qb_ + (f * 64 + l) * 8);

        // v frags: global->reg early (L2-resident; latency hidden under QK+exp)
        u16x8 vf[8];
        #pragma unroll
        for (int f = 0; f < 8; ++f)
            vf[f] = *reinterpret_cast<const u16x8*>(vc + (f * 64 + l) * 8);

        // ---- QK^T: S^T[m 0..63][n = this wave's 32], first kk uses zero C
        f32x16 s0 = __builtin_amdgcn_mfma_f32_32x32x16_bf16(__builtin_bit_cast(bf16x8, a[0]), kf[0], zro, 0, 0, 0);
        f32x16 s1 = __builtin_amdgcn_mfma_f32_32x32x16_bf16(__builtin_bit_cast(bf16x8, a[4]), kf[0], zro, 0, 0, 0);
        #pragma unroll
        for (int kk = 1; kk < 4; ++kk) {
            s0 = __builtin_amdgcn_mfma_f32_32x32x16_bf16(__builtin_bit_cast(bf16x8, a[kk]),     kf[kk], s0, 0, 0, 0);
            s1 = __builtin_amdgcn_mfma_f32_32x32x16_bf16(__builtin_bit_cast(bf16x8, a[4 + kk]), kf[kk], s1, 0, 0, 0);
        }

        // ---- no-max softmax: p = exp2(s); 4-way partial sums (short dep chains)
        float ps0 = 0.f, ps1 = 0.f, ps2 = 0.f, ps3 = 0.f;
        #pragma unroll
        for (int r = 0; r < 16; r += 4) {
            s0[r]   = EXP2F(s0[r]);   ps0 += s0[r];
            s0[r+1] = EXP2F(s0[r+1]); ps1 += s0[r+1];
            s0[r+2] = EXP2F(s0[r+2]); ps2 += s0[r+2];
            s0[r+3] = EXP2F(s0[r+3]); ps3 += s0[r+3];
        }
        #pragma unroll
        for (int r = 0; r < 16; r += 4) {
            s1[r]   = EXP2F(s1[r]);   ps0 += s1[r];
            s1[r+1] = EXP2F(s1[r+1]); ps1 += s1[r+1];
            s1[r+2] = EXP2F(s1[r+2]); ps2 += s1[r+2];
            s1[r+3] = EXP2F(s1[r+3]); ps3 += s1[r+3];
        }
        sum += (ps0 + ps1) + (ps2 + ps3);

        // ---- PV: pack bf16 + v_permlane32_swap_b32 (no shfl, no selects)
        // swap(D,S): D' = {D.lo, S.lo_from_partner}, S' = {D.hi_from_partner, S.hi}
        // -> pf = {w0,w1,w2,w3} is the correct B-frag for BOTH lane halves.
        #pragma unroll
        for (int kt = 0; kt < 4; ++kt) {
            const f32x16& sm = (kt < 2) ? s0 : s1;
            const int qA = 2 * (kt & 1);
            unsigned int w0 = pk2(sm[4*qA+0], sm[4*qA+1]);
            unsigned int w1 = pk2(sm[4*qA+2], sm[4*qA+3]);
            unsigned int w2 = pk2(sm[4*qA+4], sm[4*qA+5]);
            unsigned int w3 = pk2(sm[4*qA+6], sm[4*qA+7]);
            asm volatile("v_permlane32_swap_b32 %0, %1" : "+v"(w0), "+v"(w2));
            asm volatile("v_permlane32_swap_b32 %0, %1" : "+v"(w1), "+v"(w3));
            u32x4 pf = (u32x4){w0, w1, w2, w3};
            bf16x8 pB = __builtin_bit_cast(bf16x8, pf);
            o0 = __builtin_amdgcn_mfma_f32_32x32x16_bf16(__builtin_bit_cast(bf16x8, vf[kt]),     pB, o0, 0, 0, 0);
            o1 = __builtin_amdgcn_mfma_f32_32x32x16_bf16(__builtin_bit_cast(bf16x8, vf[4 + kt]), pB, o1, 0, 0, 0);
        }
        __syncthreads();   // drains vmcnt (next q buf staged) + closes reads of cur
    }

    // ---- epilogue: partial O^T [64ch][64row] slices + l
    sum += (float)__shfl_xor(sum, 32);
    const int t64 = (bn0 >> 6) + (w >> 1);     // 64-row tile index
    const int rowoff = 32 * (w & 1);
    const int pidx = (b * 64 + t64) * SPLITQ_T + qid;
    float* po = part + (size_t)pidx * 4096;
    #pragma unroll
    for (int r = 0; r < 16; ++r) {
        int cb = (r & 3) + 8 * (r >> 2) + 4 * hi;
        po[cb * 64 + rowoff + lo5]        = o0[r];
        po[(32 + cb) * 64 + rowoff + lo5] = o1[r];
    }
    if (hi == 0) lp[(size_t)pidx * 64 + rowoff + lo5] = sum;
}

// ------------- combine: plain sum of partials -------------
__global__ __launch_bounds__(256) void combine2(
    const float* __restrict__ part, const float* __restrict__ lp,
    float* __restrict__ outp, int splitq)
{
    __shared__ float sinv[64];
    const int orig = blockIdx.x;                   // XCD-swizzle: read XCD-local partials
    const int bid = (orig & 7) * 64 + (orig >> 3); // 512: b*64 + tile
    const int b = bid >> 6, tile = bid & 63;
    const int n0 = tile * 64;
    const int t = threadIdx.x;
    const int pb = bid * splitq;

    if (t < 64) {
        float L = 0.f;
        for (int q = 0; q < splitq; ++q) L += lp[(size_t)(pb + q) * 64 + t];
        sinv[t] = 1.0f / L;
    }
    __syncthreads();

    float* ob = outp + (size_t)b * NC * NN;
    #pragma unroll
    for (int it = 0; it < 4; ++it) {
        int idx = it * 1024 + t * 4;
        int ch = idx >> 6, r0 = idx & 63;
        f32x4 acc = (f32x4){0.f, 0.f, 0.f, 0.f};
        for (int q = 0; q < splitq; ++q) {
            f32x4 v = *reinterpret_cast<const f32x4*>(part + (size_t)(pb + q) * 4096 + idx);
            acc += v;
        }
        f32x4 res;
        #pragma unroll
        for (int u = 0; u < 4; ++u) res[u] = acc[u] * sinv[r0 + u];
        *reinterpret_cast<f32x4*>(ob + (size_t)ch * NN + n0 + r0) = res;
    }
}

// ---------------- non-split attn2 (verified R3 fallback) ----------------
__global__ __launch_bounds__(128) void attn2(
    const float* __restrict__ kp,
    const unsigned short* __restrict__ qfo,
    const unsigned short* __restrict__ vfo,
    float* __restrict__ outp)
{
    __shared__ unsigned short sb[2][2 * CHUNK_U16];
    const int orig = blockIdx.x;
    const int bid  = (orig & 7) * 64 + (orig >> 3);
    const int b = bid >> 6, nt = bid & 63;
    const int n0 = nt * 64;
    const int tid = threadIdx.x;
    const int w = tid >> 6, l = tid & 63;
    const int lo5 = l & 31, hi = l >> 5;
    const int nrow = n0 + 32 * w + lo5;
    const float kscale = 0.125f * 1.44269504088896f;
    const float* kb = kp + (size_t)b * NC * NN;
    bf16x8 kf[4];
    #pragma unroll
    for (int kk = 0; kk < 4; ++kk) {
        u16x8 t;
        #pragma unroll
        for (int e = 0; e < 8; ++e)
            t[e] = f2bf(kscale * kb[(size_t)(16 * kk + 8 * hi + e) * NN + nrow]);
        kf[kk] = __builtin_bit_cast(bf16x8, t);
    }
    const unsigned short* qg = qfo + (size_t)(b * 64) * CHUNK_U16;
    const unsigned short* vg = vfo + (size_t)(b * 64) * CHUNK_U16;
    auto stage = [&](int mc, int buf) {
        const unsigned short* gq = qg + (size_t)mc * CHUNK_U16;
        const unsigned short* gv = vg + (size_t)mc * CHUNK_U16;
        #pragma unroll
        for (int i = 0; i < 4; ++i) {
            int seg = w * 4 + i;
            int off = seg * 512 + l * 8;
            __builtin_amdgcn_global_load_lds(
                (const __attribute__((address_space(1))) void*)(gq + off),
                (__attribute__((address_space(3))) void*)(&sb[buf][seg * 512]), 16, 0, 0);
            __builtin_amdgcn_global_load_lds(
                (const __attribute__((address_space(1))) void*)(gv + off),
                (__attribute__((address_space(3))) void*)(&sb[buf][CHUNK_U16 + seg * 512]), 16, 0, 0);
        }
    };
    stage(0, 0);
    __syncthreads();
    f32x16 o0, o1;
    #pragma unroll
    for (int r = 0; r < 16; ++r) { o0[r] = 0.f; o1[r] = 0.f; }
    float m_run = -1e30f, l_run = 0.f;
    for (int mc = 0; mc < NCHUNK; ++mc) {
        const int cur = mc & 1;
        if (mc + 1 < NCHUNK) stage(mc + 1, cur ^ 1);
        const unsigned short* qb_ = &sb[cur][0];
        const unsigned short* vb_ = &sb[cur][CHUNK_U16];
        f32x16 s0, s1;
        #pragma unroll
        for (int r = 0; r < 16; ++r) { s0[r] = 0.f; s1[r] = 0.f; }
        #pragma unroll
        for (int kk = 0; kk < 4; ++kk) {
            u16x8 a0 = *reinterpret_cast<const u16x8*>(qb_ + ((0 * 4 + kk) * 64 + l) * 8);
            u16x8 a1 = *reinterpret_cast<const u16x8*>(qb_ + ((1 * 4 + kk) * 64 + l) * 8);
            s0 = __builtin_amdgcn_mfma_f32_32x32x16_bf16(__builtin_bit_cast(bf16x8, a0), kf[kk], s0, 0, 0, 0);
            s1 = __builtin_amdgcn_mfma_f32_32x32x16_bf16(__builtin_bit_cast(bf16x8, a1), kf[kk], s1, 0, 0, 0);
        }
        float pmax = s0[0];
        #pragma unroll
        for (int r = 1; r < 16; ++r) pmax = fmaxf(pmax, s0[r]);
        #pragma unroll
        for (int r = 0; r < 16; ++r) pmax = fmaxf(pmax, s1[r]);
        pmax = fmaxf(pmax, (float)__shfl_xor(pmax, 32));
        const float mn = fmaxf(m_run, pmax);
        const float alpha = EXP2F(m_run - mn);
        float sum = 0.f;
        #pragma unroll
        for (int r = 0; r < 16; ++r) { s0[r] = EXP2F(s0[r] - mn); sum += s0[r]; }
        #pragma unroll
        for (int r = 0; r < 16; ++r) { s1[r] = EXP2F(s1[r] - mn); sum += s1[r]; }
        sum += (float)__shfl_xor(sum, 32);
        l_run = l_run * alpha + sum;
        m_run = mn;
        #pragma unroll
        for (int r = 0; r < 16; ++r) { o0[r] *= alpha; o1[r] *= alpha; }
        #pragma unroll
        for (int kt = 0; kt < 4; ++kt) {
            const f32x16& sm = (kt < 2) ? s0 : s1;
            const int qA = 2 * (kt & 1);
            unsigned int dA0 = pk2(sm[4 * qA + 0], sm[4 * qA + 1]);
            unsigned int dA1 = pk2(sm[4 * qA + 2], sm[4 * qA + 3]);
            unsigned int dB0 = pk2(sm[4 * qA + 4], sm[4 * qA + 5]);
            unsigned int dB1 = pk2(sm[4 * qA + 6], sm[4 * qA + 7]);
            unsigned int sA0 = (unsigned int)__shfl_xor((int)dA0, 32);
            unsigned int sA1 = (unsigned int)__shfl_xor((int)dA1, 32);
            unsigned int sB0 = (unsigned int)__shfl_xor((int)dB0, 32);
            unsigned int sB1 = (unsigned int)__shfl_xor((int)dB1, 32);
            u32x4 pf;
            if (hi == 0) pf = (u32x4){dA0, dA1, sA0, sA1};
            else         pf = (u32x4){sB0, sB1, dB0, dB1};
            bf16x8 pB = __builtin_bit_cast(bf16x8, pf);
            u16x8 v0 = *reinterpret_cast<const u16x8*>(vb_ + ((0 * 4 + kt) * 64 + l) * 8);
            u16x8 v1 = *reinterpret_cast<const u16x8*>(vb_ + ((1 * 4 + kt) * 64 + l) * 8);
            o0 = __builtin_amdgcn_mfma_f32_32x32x16_bf16(__builtin_bit_cast(bf16x8, v0), pB, o0, 0, 0, 0);
            o1 = __builtin_amdgcn_mfma_f32_32x32x16_bf16(__builtin_bit_cast(bf16x8, v1), pB, o1, 0, 0, 0);
        }
        __syncthreads();
    }
    const float inv = 1.0f / l_run;
    float* ob = outp + (size_t)b * NC * NN;
    #pragma unroll
    for (int r = 0; r < 16; ++r) {
        int cb = (r & 3) + 8 * (r >> 2) + 4 * hi;
        ob[(size_t)cb * NN + n0 + 32 * w + lo5]        = o0[r] * inv;
        ob[(size_t)(32 + cb) * NN + n0 + 32 * w + lo5] = o1[r] * inv;
    }
}

// ---------------- round-1 fallback (no ws) ----------------
__global__ __launch_bounds__(256) void attn_fwd(
    const float* __restrict__ kp, const float* __restrict__ qp,
    const float* __restrict__ vp, float* __restrict__ outp)
{
    __shared__ unsigned short qs[8][64][8];
    __shared__ unsigned short vs[8][64][8];
    __shared__ unsigned short ps[4][2][64][8];
    const int orig = blockIdx.x;
    const int bid  = (orig & 7) * 64 + (orig >> 3);
    const int b  = bid >> 6;
    const int n0 = (bid & 63) * 64;
    const int tid = threadIdx.x;
    const int w = tid >> 6, l = tid & 63, g = l >> 4, j = l & 15;
    const float* kb = kp + (size_t)b * NC * NN;
    const float* qb = qp + (size_t)b * NC * NN;
    const float* vb = vp + (size_t)b * NC * NN;
    bf16x8 ak[2];
    #pragma unroll
    for (int kk = 0; kk < 2; ++kk) {
        u16x8 tmp;
        #pragma unroll
        for (int e = 0; e < 8; ++e)
            tmp[e] = f2bf(kb[(size_t)(32*kk + 8*g + e) * NN + (n0 + 16*w + j)]);
        ak[kk] = __builtin_bit_cast(bf16x8, tmp);
    }
    f32x4 o[4];
    float m_run[4], l_run[4];
    #pragma unroll
    for (int ct = 0; ct < 4; ++ct) o[ct] = (f32x4){0.f,0.f,0.f,0.f};
    #pragma unroll
    for (int r = 0; r < 4; ++r) { m_run[r] = -1e30f; l_run[r] = 0.0f; }
    for (int m0 = 0; m0 < NN; m0 += 64) {
        __syncthreads();
        #pragma unroll
        for (int it = 0; it < 4; ++it) {
            int f = tid + 256*it;
            int c = f >> 4, m4 = (f & 15) << 2;
            f32x4 qv = *reinterpret_cast<const f32x4*>(qb + (size_t)c*NN + m0 + m4);
            f32x4 vv = *reinterpret_cast<const f32x4*>(vb + (size_t)c*NN + m0 + m4);
            int kkq = c >> 5, eq = c & 7, gq = (c >> 3) & 3, tq = m4 >> 4;
            #pragma unroll
            for (int u = 0; u < 4; ++u)
                qs[kkq*4 + tq][16*gq + ((m4 + u) & 15)][eq] = f2bf(qv[u]);
            int ctv = c >> 4, jv = c & 15, kkv = m4 >> 5, gv = (m4 >> 3) & 3, ev = m4 & 7;
            #pragma unroll
            for (int u = 0; u < 4; ++u)
                vs[kkv*4 + ctv][16*gv + jv][ev + u] = f2bf(vv[u]);
        }
        __syncthreads();
        f32x4 s[4];
        #pragma unroll
        for (int t = 0; t < 4; ++t) {
            f32x4 acc = (f32x4){0.f,0.f,0.f,0.f};
            #pragma unroll
            for (int kk = 0; kk < 2; ++kk) {
                u16x8 raw = *reinterpret_cast<const u16x8*>(&qs[kk*4 + t][l][0]);
                acc = __builtin_amdgcn_mfma_f32_16x16x32_bf16(ak[kk], __builtin_bit_cast(bf16x8, raw), acc, 0,0,0);
            }
            s[t] = acc * 0.125f;
        }
        float alpha[4];
        #pragma unroll
        for (int r = 0; r < 4; ++r) {
            float m1 = fmaxf(fmaxf(s[0][r], s[1][r]), fmaxf(s[2][r], s[3][r]));
            #pragma unroll
            for (int off = 1; off < 16; off <<= 1) m1 = fmaxf(m1, __shfl_xor(m1, off));
            float mn = fmaxf(m_run[r], m1);
            alpha[r] = __expf(m_run[r] - mn);
            m_run[r] = mn;
            float acc = 0.0f;
            #pragma unroll
            for (int t = 0; t < 4; ++t) { float p = __expf(s[t][r] - mn); s[t][r] = p; acc += p; }
            #pragma unroll
            for (int off = 1; off < 16; off <<= 1) acc += __shfl_xor(acc, off);
            l_run[r] = l_run[r] * alpha[r] + acc;
        }
        {
            int srcl = (j >> 2) << 4;
            float a0 = __shfl(alpha[0], srcl), a1 = __shfl(alpha[1], srcl);
            float a2 = __shfl(alpha[2], srcl), a3 = __shfl(alpha[3], srcl);
            int rs = j & 3;
            float ac = (rs==0)?a0:(rs==1)?a1:(rs==2)?a2:a3;
            #pragma unroll
            for (int ct = 0; ct < 4; ++ct) o[ct] *= ac;
        }
        #pragma unroll
        for (int t = 0; t < 4; ++t) {
            int m = 16*t + j;
            #pragma unroll
            for (int r = 0; r < 4; ++r)
                ps[w][m >> 5][((m >> 3) & 3)*16 + 4*g + r][m & 7] = f2bf(s[t][r]);
        }
        asm volatile("s_waitcnt lgkmcnt(0)" ::: "memory");
        #pragma unroll
        for (int kk2 = 0; kk2 < 2; ++kk2) {
            u16x8 rp = *reinterpret_cast<const u16x8*>(&ps[w][kk2][l][0]);
            bf16x8 bp = __builtin_bit_cast(bf16x8, rp);
            #pragma unroll
            for (int ct = 0; ct < 4; ++ct) {
                u16x8 rv = *reinterpret_cast<const u16x8*>(&vs[kk2*4 + ct][l][0]);
                o[ct] = __builtin_amdgcn_mfma_f32_16x16x32_bf16(__builtin_bit_cast(bf16x8, rv), bp, o[ct], 0,0,0);
            }
        }
    }
    {
        int srcl = (j >> 2) << 4;
        float l0 = __shfl(l_run[0], srcl), l1 = __shfl(l_run[1], srcl);
        float l2 = __shfl(l_run[2], srcl), l3 = __shfl(l_run[3], srcl);
        int rs = j & 3;
        float lc = (rs==0)?l0:(rs==1)?l1:(rs==2)?l2:l3;
        float inv = 1.0f / lc;
        #pragma unroll
        for (int ct = 0; ct < 4; ++ct)
            #pragma unroll
            for (int r = 0; r < 4; ++r)
                outp[(size_t)b*NC*NN + (size_t)(16*ct + 4*g + r)*NN + (n0 + 16*w + j)] = o[ct][r] * inv;
    }
}

extern "C" void kernel_launch(void* const* d_in, const int* in_sizes, int n_in,
                              void* d_out, int out_size, void* d_ws, size_t ws_size,
                              hipStream_t stream) {
    const float* kp = (const float*)d_in[0];
    const float* qp = (const float*)d_in[1];
    const float* vp = (const float*)d_in[2];
    float* op = (float*)d_out;
    const size_t FRAG_BYTES = (size_t)2 * NB * NCHUNK * CHUNK_U16 * sizeof(unsigned short); // 8 MB
    unsigned short* qfo = (unsigned short*)d_ws;
    unsigned short* vfo = qfo + (size_t)NB * NCHUNK * CHUNK_U16;

    const size_t NEED = FRAG_BYTES
        + (size_t)NB * 64 * SPLITQ * 4096 * sizeof(float)   // partials (32 MB)
        + (size_t)NB * 64 * SPLITQ * 64 * sizeof(float);    // l sums

    if (ws_size >= NEED) {
        float* part = (float*)((char*)d_ws + FRAG_BYTES);
        float* lpp  = part + (size_t)NB * 64 * SPLITQ * 4096;
        hipLaunchKernelGGL(prepass, dim3(NB * NCHUNK), dim3(256), 0, stream, qp, vp, qfo, vfo);
        hipLaunchKernelGGL(attn8<SPLITQ>, dim3(NB * SPLITQ * (NN / 128)), dim3(256), 0, stream,
                           kp, qfo, vfo, part, lpp);
        hipLaunchKernelGGL(combine2, dim3(NB * 64), dim3(256), 0, stream, part, lpp, op, SPLITQ);
    } else if (ws_size >= FRAG_BYTES) {
        hipLaunchKernelGGL(prepass, dim3(NB * NCHUNK), dim3(256), 0, stream, qp, vp, qfo, vfo);
        hipLaunchKernelGGL(attn2, dim3(NB * NCHUNK), dim3(128), 0, stream, kp, qfo, vfo, op);
    } else {
        hipLaunchKernelGGL(attn_fwd, dim3(512), dim3(256), 0, stream, kp, qp, vp, op);
    }
}